// Round 8
// baseline (6585.536 us; speedup 1.0000x reference)
//
#include <hip/hip_runtime.h>
#include <math.h>

#define NODES   325
#define TOPK    8
#define B_SZ    8
#define T_LEN   64
#define EPS     1e-5f
#define NTOK    ((size_t)B_SZ * T_LEN * NODES)   /* 166,400 */

__device__ __forceinline__ float waveSum64(float v){
  #pragma unroll
  for(int m=1;m<64;m<<=1) v += __shfl_xor(v, m, 64);
  return v;
}
__device__ __forceinline__ float groupSum16(float v){
  v += __shfl_xor(v, 1, 64);
  v += __shfl_xor(v, 2, 64);
  v += __shfl_xor(v, 4, 64);
  v += __shfl_xor(v, 8, 64);
  return v;
}
__device__ __forceinline__ float fma4(float4 w, float4 s, float acc){
  acc = fmaf(w.x, s.x, acc);
  acc = fmaf(w.y, s.y, acc);
  acc = fmaf(w.z, s.z, acc);
  return fmaf(w.w, s.w, acc);
}

// ================= K1: fused LN1 + Mamba + K/V projection =================
// grid = B*NODES blocks, 128 threads; thread d owns D_INNER channel d.
// Processes TB=8 tokens per iteration (5 barriers / 8 tokens).
// Writes xT into d_out (fp32) and K|V (fp32, [tok][128]) into ws.
__global__ __launch_bounds__(128)
void mamba_fused(const float* __restrict__ x,
                 const float* __restrict__ ln1_g, const float* __restrict__ ln1_b,
                 const float* __restrict__ in_w,
                 const float* __restrict__ conv_w, const float* __restrict__ conv_b,
                 const float* __restrict__ xp_w,
                 const float* __restrict__ dt_w, const float* __restrict__ dt_b,
                 const float* __restrict__ A_log, const float* __restrict__ Dss,
                 const float* __restrict__ out_w,
                 const float* __restrict__ k_w, const float* __restrict__ k_b,
                 const float* __restrict__ v_w, const float* __restrict__ v_b,
                 float* __restrict__ xT, float* __restrict__ KV)
{
  const int bn  = blockIdx.x;
  const int b   = bn / NODES;
  const int n   = bn % NODES;
  const int tid = threadIdx.x;
  const int l   = tid & 15;      // lane within 16-group
  const int g   = tid >> 4;      // token group 0..7
  const int d   = tid;           // D_INNER channel

  __shared__ float s_tok[8][68];   // raw tokens (residual)
  __shared__ float s_h[8][68];     // LN'd tokens
  __shared__ float s_xc[8][132];   // conv+silu
  __shared__ float s_dbl[8][36];   // dt_raw[4] | B[16] | C[16]
  __shared__ float s_y[8][132];    // pre-out_proj
  __shared__ float s_xn[8][68];    // result tokens

  // persistent per-thread params
  float A_d[16], hs[16];
  #pragma unroll
  for(int s=0;s<16;s++){ A_d[s] = -__expf(A_log[d*16+s]); hs[s] = 0.f; }
  const float4 cw  = *(const float4*)(conv_w + d*4);
  const float4 dtw = *(const float4*)(dt_w  + d*4);
  const float cb  = conv_b[d], dtb = dt_b[d], Dd = Dss[d];
  const float4 g4 = *(const float4*)(ln1_g + 4*l);
  const float4 b4 = *(const float4*)(ln1_b + 4*l);
  const float* kvw = (tid < 64) ? (k_w + tid*64) : (v_w + (tid-64)*64);
  const float  kvb = (tid < 64) ? k_b[tid] : v_b[tid-64];
  float xm1 = 0.f, xm2 = 0.f, xm3 = 0.f;   // xi history (causal conv)

  for(int it=0; it<8; ++it){
    const int t0 = it*8;

    // ---- load + LN1: 16-lane group g handles token t0+g ----
    {
      const size_t tokg = ((size_t)(b*T_LEN + t0 + g)*NODES + n);
      float4 x4 = *(const float4*)(x + tokg*64 + 4*l);
      float m = groupSum16(x4.x + x4.y + x4.z + x4.w) * (1.f/64.f);
      float4 c4 = make_float4(x4.x-m, x4.y-m, x4.z-m, x4.w-m);
      float var = groupSum16(c4.x*c4.x + c4.y*c4.y + c4.z*c4.z + c4.w*c4.w) * (1.f/64.f);
      float rs = rsqrtf(var + EPS);
      float4 h4 = make_float4(c4.x*rs*g4.x + b4.x, c4.y*rs*g4.y + b4.y,
                              c4.z*rs*g4.z + b4.z, c4.w*rs*g4.w + b4.w);
      *(float4*)&s_tok[g][4*l] = x4;
      *(float4*)&s_h[g][4*l]   = h4;
    }
    __syncthreads();   // A

    // ---- in_proj (rows d and d+128) for 8 tokens, then conv+silu ----
    float xi[8] = {0,0,0,0,0,0,0,0};
    float zz[8] = {0,0,0,0,0,0,0,0};
    {
      const float* w0r = in_w + d*64;
      const float* w1r = in_w + (d+128)*64;
      #pragma unroll
      for(int q=0;q<16;q++){
        float4 w0 = *(const float4*)(w0r + 4*q);
        float4 w1 = *(const float4*)(w1r + 4*q);
        #pragma unroll
        for(int t=0;t<8;t++){
          float4 h4 = *(const float4*)&s_h[t][4*q];
          xi[t] = fma4(w0, h4, xi[t]);
          zz[t] = fma4(w1, h4, zz[t]);
        }
      }
    }
    float xcr[8];
    #pragma unroll
    for(int t=0;t<8;t++){
      float a = cb + cw.x*xm3 + cw.y*xm2 + cw.z*xm1 + cw.w*xi[t];
      xm3 = xm2; xm2 = xm1; xm1 = xi[t];
      float xc = a / (1.f + __expf(-a));
      xcr[t] = xc;
      s_xc[t][d] = xc;
    }
    __syncthreads();   // B

    // ---- x_proj: token g; rows l, l+16, l+32(if l<4) ----
    {
      const float* xp1 = xp_w + l*128;
      const float* xp2 = xp_w + (l+16)*128;
      const float* xp3 = xp_w + ((l<4) ? (l+32) : 0)*128;
      float a1=0.f, a2=0.f, a3=0.f;
      #pragma unroll
      for(int q=0;q<32;q++){
        float4 cc = *(const float4*)&s_xc[g][4*q];
        a1 = fma4(*(const float4*)(xp1 + 4*q), cc, a1);
        a2 = fma4(*(const float4*)(xp2 + 4*q), cc, a2);
        a3 = fma4(*(const float4*)(xp3 + 4*q), cc, a3);
      }
      s_dbl[g][l]    = a1;
      s_dbl[g][l+16] = a2;
      if(l < 4) s_dbl[g][l+32] = a3;
    }
    __syncthreads();   // C

    // ---- dt + selective scan + readout (thread d, 8 serial steps) ----
    #pragma unroll
    for(int t=0;t<8;t++){
      float4 dr = *(const float4*)&s_dbl[t][0];
      float dtv = dtb;
      dtv = fmaf(dr.x, dtw.x, dtv);
      dtv = fmaf(dr.y, dtw.y, dtv);
      dtv = fmaf(dr.z, dtw.z, dtv);
      dtv = fmaf(dr.w, dtw.w, dtv);
      dtv = fmaxf(dtv, 0.f) + log1pf(__expf(-fabsf(dtv)));
      float dx = dtv * xcr[t];
      float y = 0.f;
      #pragma unroll
      for(int s=0;s<16;s++){
        float dA = __expf(dtv * A_d[s]);
        hs[s] = fmaf(hs[s], dA, dx * s_dbl[t][4+s]);
        y     = fmaf(hs[s], s_dbl[t][20+s], y);
      }
      y = y + Dd * xcr[t];
      y = y * (zz[t] / (1.f + __expf(-zz[t])));   // * silu(z)
      s_y[t][d] = y;
    }
    __syncthreads();   // D

    // ---- out_proj + residual: row r = tid&63, 4 tokens per wave ----
    {
      const int r  = tid & 63;
      const int tb = (tid >> 6) * 4;
      const float* wr = out_w + r*128;
      float a0=0.f, a1=0.f, a2=0.f, a3=0.f;
      #pragma unroll
      for(int q=0;q<32;q++){
        float4 w4 = *(const float4*)(wr + 4*q);
        a0 = fma4(w4, *(const float4*)&s_y[tb+0][4*q], a0);
        a1 = fma4(w4, *(const float4*)&s_y[tb+1][4*q], a1);
        a2 = fma4(w4, *(const float4*)&s_y[tb+2][4*q], a2);
        a3 = fma4(w4, *(const float4*)&s_y[tb+3][4*q], a3);
      }
      float acc[4] = {a0,a1,a2,a3};
      #pragma unroll
      for(int tt=0;tt<4;tt++){
        const int t = tb + tt;
        const size_t tok = ((size_t)(b*T_LEN + t0 + t)*NODES + n);
        float xn = s_tok[t][r] + acc[tt];
        s_xn[t][r] = xn;
        xT[tok*64 + r] = xn;
      }
    }
    __syncthreads();   // E

    // ---- K/V projection of the 8 new tokens ----
    {
      float kv[8] = {kvb,kvb,kvb,kvb,kvb,kvb,kvb,kvb};
      #pragma unroll
      for(int q=0;q<16;q++){
        float4 w4 = *(const float4*)(kvw + 4*q);
        #pragma unroll
        for(int t=0;t<8;t++){
          kv[t] = fma4(w4, *(const float4*)&s_xn[t][4*q], kv[t]);
        }
      }
      #pragma unroll
      for(int t=0;t<8;t++){
        const size_t tok = ((size_t)(b*T_LEN + t0 + t)*NODES + n);
        KV[tok*128 + tid] = kv[t];
      }
    }
    // no barrier needed: next iteration touches only s_tok/s_h before barrier A
  }
}

// ================= K2: graph attention + gate + LN2 (in-place on d_out) ======
// grid = NTOK blocks, 64 threads; reads own token from xT(=d_out) + KV(ws),
// overwrites own token with the final output.
__global__ __launch_bounds__(64)
void attn_fused(float* __restrict__ xT, const float* __restrict__ KV,
                const int* __restrict__ nbr,
                const float* __restrict__ q_w, const float* __restrict__ q_b,
                const float* __restrict__ o_w, const float* __restrict__ o_b,
                const float* __restrict__ g1_w, const float* __restrict__ g1_b,
                const float* __restrict__ g2_w, const float* __restrict__ g2_b,
                const float* __restrict__ ln2_g, const float* __restrict__ ln2_b)
{
  const int idx = blockIdx.x;           // (b*T + t)*NODES + n
  const int n   = idx % NODES;
  const int bt  = idx / NODES;
  const int j   = threadIdx.x;

  __shared__ float s_x[64];
  __shared__ float s_og[64];
  __shared__ float s_gate;

  const float xv = xT[(size_t)idx*64 + j];
  s_x[j] = xv;

  // gather neighbor K/V early (precomputed, fp32)
  const size_t base = (size_t)bt * NODES;
  float Kk[TOPK], Vv[TOPK];
  #pragma unroll
  for(int k=0;k<TOPK;k++){
    const int nb = nbr[n*TOPK + k];
    const float* kvp = KV + (base + nb)*128;
    Kk[k] = kvp[j];
    Vv[k] = kvp[64 + j];
  }
  __syncthreads();

  // Q projection (row j)
  float Qj = q_b[j];
  {
    const float* qr = q_w + j*64;
    #pragma unroll
    for(int q=0;q<16;q++)
      Qj = fma4(*(const float4*)(qr + 4*q), *(const float4*)&s_x[4*q], Qj);
  }

  // head-wise scores (16-lane reductions), softmax over 8
  float sc[TOPK];
  #pragma unroll
  for(int k=0;k<TOPK;k++) sc[k] = groupSum16(Qj * Kk[k]) * 0.25f;  // hd^-0.5
  float m = sc[0];
  #pragma unroll
  for(int k=1;k<TOPK;k++) m = fmaxf(m, sc[k]);
  float ssum = 0.f;
  #pragma unroll
  for(int k=0;k<TOPK;k++){ sc[k] = __expf(sc[k]-m); ssum += sc[k]; }
  const float inv = 1.f/ssum;
  float og = 0.f;
  #pragma unroll
  for(int k=0;k<TOPK;k++) og = fmaf(sc[k]*inv, Vv[k], og);
  s_og[j] = og;
  __syncthreads();

  // O projection
  float xg = o_b[j];
  {
    const float* orow = o_w + j*64;
    #pragma unroll
    for(int q=0;q<16;q++)
      xg = fma4(*(const float4*)(orow + 4*q), *(const float4*)&s_og[4*q], xg);
  }

  // scalar gate: sigmoid(gelu(x@g1^T+b1) @ g2^T + b2)
  if(j < 16){
    float u = g1_b[j];
    const float* g1r = g1_w + j*64;
    #pragma unroll
    for(int q=0;q<16;q++)
      u = fma4(*(const float4*)(g1r + 4*q), *(const float4*)&s_x[4*q], u);
    u = 0.5f * u * (1.f + erff(u * 0.70710678118654752f));   // exact gelu
    float contrib = groupSum16(u * g2_w[j]);
    if(j == 0) s_gate = 1.f / (1.f + __expf(-(contrib + g2_b[0])));
  }
  __syncthreads();

  const float gg = s_gate;
  const float o  = xv + gg * (xg - xv);

  // LN2 across the 64 lanes
  float mm  = waveSum64(o) * (1.f/64.f);
  float c   = o - mm;
  float var = waveSum64(c*c) * (1.f/64.f);
  xT[(size_t)idx*64 + j] = c * rsqrtf(var + EPS) * ln2_g[j] + ln2_b[j];
}

extern "C" void kernel_launch(void* const* d_in, const int* in_sizes, int n_in,
                              void* d_out, int out_size, void* d_ws, size_t ws_size,
                              hipStream_t stream)
{
  const float* x      = (const float*)d_in[0];
  const int*   nbr    = (const int*  )d_in[1];
  const float* ln1_g  = (const float*)d_in[2];
  const float* ln1_b  = (const float*)d_in[3];
  const float* in_w   = (const float*)d_in[4];
  const float* conv_w = (const float*)d_in[5];
  const float* conv_b = (const float*)d_in[6];
  const float* xp_w   = (const float*)d_in[7];
  const float* dt_w   = (const float*)d_in[8];
  const float* dt_b   = (const float*)d_in[9];
  const float* A_log  = (const float*)d_in[10];
  const float* Dss    = (const float*)d_in[11];
  const float* out_w  = (const float*)d_in[12];
  const float* q_w    = (const float*)d_in[13];
  const float* q_b    = (const float*)d_in[14];
  const float* k_w    = (const float*)d_in[15];
  const float* k_b    = (const float*)d_in[16];
  const float* v_w    = (const float*)d_in[17];
  const float* v_b    = (const float*)d_in[18];
  const float* o_w    = (const float*)d_in[19];
  const float* o_b    = (const float*)d_in[20];
  const float* g1_w   = (const float*)d_in[21];
  const float* g1_b   = (const float*)d_in[22];
  const float* g2_w   = (const float*)d_in[23];
  const float* g2_b   = (const float*)d_in[24];
  const float* ln2_g  = (const float*)d_in[25];
  const float* ln2_b  = (const float*)d_in[26];

  float* outp = (float*)d_out;     // holds xT between K1 and K2, final out after K2
  float* KV   = (float*)d_ws;      // NTOK*128 fp32 = 85.2 MB (ws capacity proven in R6)

  mamba_fused<<<dim3(B_SZ*NODES), dim3(128), 0, stream>>>(
      x, ln1_g, ln1_b, in_w, conv_w, conv_b, xp_w, dt_w, dt_b, A_log, Dss,
      out_w, k_w, k_b, v_w, v_b, outp, KV);

  attn_fused<<<dim3((unsigned)NTOK), dim3(64), 0, stream>>>(
      outp, KV, nbr, q_w, q_b, o_w, o_b, g1_w, g1_b, g2_w, g2_b, ln2_g, ln2_b);
}

// Round 9
// 5885.986 us; speedup vs baseline: 1.1189x; 1.1189x over previous
//
#include <hip/hip_runtime.h>
#include <hip/hip_bf16.h>
#include <math.h>

#define NODES   325
#define TOPK    8
#define B_SZ    8
#define T_LEN   64
#define EPS     1e-5f
#define NTOK    ((size_t)B_SZ * T_LEN * NODES)   /* 166,400 */

typedef __hip_bfloat16 bf16;
__device__ __forceinline__ float b2f(bf16 v){ return __bfloat162float(v); }

__device__ __forceinline__ float waveSum64(float v){
  #pragma unroll
  for(int m=1;m<64;m<<=1) v += __shfl_xor(v, m, 64);
  return v;
}
__device__ __forceinline__ float groupSum16(float v){
  v += __shfl_xor(v, 1, 64);
  v += __shfl_xor(v, 2, 64);
  v += __shfl_xor(v, 4, 64);
  v += __shfl_xor(v, 8, 64);
  return v;
}

// ============ weight transpose prep (runs once per launch, ~42k elems) ======
// ws float layout (after KV bf16 region):
//   in_wT  [64][256]   @ 0      (in_w  256x64)
//   out_wT [128][64]   @ 16384  (out_w  64x128)
//   k_wT   [64][64]    @ 24576
//   v_wT   [64][64]    @ 28672
//   q_wT   [64][64]    @ 32768
//   o_wT   [64][64]    @ 36864
//   g1_wT  [64][16]    @ 40960  (g1_w  16x64)
__global__ __launch_bounds__(256)
void transpose_prep(const float* __restrict__ in_w, const float* __restrict__ out_w,
                    const float* __restrict__ k_w,  const float* __restrict__ v_w,
                    const float* __restrict__ q_w,  const float* __restrict__ o_w,
                    const float* __restrict__ g1_w, float* __restrict__ T)
{
  const int bid = blockIdx.x, tid = threadIdx.x;
  if(bid < 64){                       // in_w 256x64
    int e = bid*256 + tid;  int r = e >> 6, c = e & 63;
    T[c*256 + r] = in_w[e];
  } else if(bid < 96){                // out_w 64x128
    int e = (bid-64)*256 + tid;  int r = e >> 7, c = e & 127;
    T[16384 + c*64 + r] = out_w[e];
  } else if(bid < 112){               // k_w 64x64
    int e = (bid-96)*256 + tid;  int r = e >> 6, c = e & 63;
    T[24576 + c*64 + r] = k_w[e];
  } else if(bid < 128){               // v_w
    int e = (bid-112)*256 + tid; int r = e >> 6, c = e & 63;
    T[28672 + c*64 + r] = v_w[e];
  } else if(bid < 144){               // q_w
    int e = (bid-128)*256 + tid; int r = e >> 6, c = e & 63;
    T[32768 + c*64 + r] = q_w[e];
  } else if(bid < 160){               // o_w
    int e = (bid-144)*256 + tid; int r = e >> 6, c = e & 63;
    T[36864 + c*64 + r] = o_w[e];
  } else {                            // g1_w 16x64 (4 blocks)
    int e = (bid-160)*256 + tid; int r = e >> 6, c = e & 63;
    T[40960 + c*16 + r] = g1_w[e];
  }
}

// ================= K1: fused LN1 + Mamba + K/V projection =================
// grid = B*NODES blocks, 128 threads; thread d owns D_INNER channel d.
// TB=8 tokens per iteration; all big dots use transposed (coalesced) weights.
__global__ __launch_bounds__(128, 2)
void mamba_fused(const float* __restrict__ x,
                 const float* __restrict__ ln1_g, const float* __restrict__ ln1_b,
                 const float* __restrict__ in_wT,
                 const float* __restrict__ conv_w, const float* __restrict__ conv_b,
                 const float* __restrict__ xp_w,
                 const float* __restrict__ dt_w, const float* __restrict__ dt_b,
                 const float* __restrict__ A_log, const float* __restrict__ Dss,
                 const float* __restrict__ out_wT,
                 const float* __restrict__ k_wT, const float* __restrict__ k_b,
                 const float* __restrict__ v_wT, const float* __restrict__ v_b,
                 float* __restrict__ xT, bf16* __restrict__ KV)
{
  const int bn  = blockIdx.x;
  const int b   = bn / NODES;
  const int n   = bn % NODES;
  const int tid = threadIdx.x;
  const int l   = tid & 15;      // lane within 16-group
  const int g   = tid >> 4;      // token group 0..7
  const int d   = tid;           // D_INNER channel

  __shared__ float s_tok[8][68];   // raw tokens (residual)
  __shared__ float s_h[8][68];     // LN'd tokens
  __shared__ float s_xc[8][132];   // conv+silu
  __shared__ float s_dbl[8][36];   // dt_raw[4] | B[16] | C[16]
  __shared__ float s_y[8][132];    // pre-out_proj
  __shared__ float s_xn[8][68];    // result tokens

  float A_d[16], hs[16];
  #pragma unroll
  for(int s=0;s<16;s++){ A_d[s] = -__expf(A_log[d*16+s]); hs[s] = 0.f; }
  const float4 cw  = *(const float4*)(conv_w + d*4);
  const float4 dtw = *(const float4*)(dt_w  + d*4);
  const float cb  = conv_b[d], dtb = dt_b[d], Dd = Dss[d];
  const float4 g4 = *(const float4*)(ln1_g + 4*l);
  const float4 b4 = *(const float4*)(ln1_b + 4*l);
  const float* kvT = (tid < 64) ? k_wT : v_wT;
  const float  kvb = (tid < 64) ? k_b[tid] : v_b[tid-64];
  const int    r63 = tid & 63;
  float xm1 = 0.f, xm2 = 0.f, xm3 = 0.f;   // xi history (causal conv)

  for(int it=0; it<8; ++it){
    const int t0 = it*8;

    // ---- A: load + LN1 (16-lane group g -> token t0+g) ----
    {
      const size_t tokg = ((size_t)(b*T_LEN + t0 + g)*NODES + n);
      float4 x4 = *(const float4*)(x + tokg*64 + 4*l);
      float m = groupSum16(x4.x + x4.y + x4.z + x4.w) * (1.f/64.f);
      float4 c4 = make_float4(x4.x-m, x4.y-m, x4.z-m, x4.w-m);
      float var = groupSum16(c4.x*c4.x + c4.y*c4.y + c4.z*c4.z + c4.w*c4.w) * (1.f/64.f);
      float rs = rsqrtf(var + EPS);
      *(float4*)&s_tok[g][4*l] = x4;
      float4 h4 = make_float4(c4.x*rs*g4.x + b4.x, c4.y*rs*g4.y + b4.y,
                              c4.z*rs*g4.z + b4.z, c4.w*rs*g4.w + b4.w);
      *(float4*)&s_h[g][4*l] = h4;
    }
    __syncthreads();   // A

    // ---- in_proj via transposed weights (coalesced) ----
    float xi[8] = {0,0,0,0,0,0,0,0};
    float zz[8] = {0,0,0,0,0,0,0,0};
    #pragma unroll
    for(int c4i=0;c4i<16;c4i++){
      float4 h4[8];
      #pragma unroll
      for(int t=0;t<8;t++) h4[t] = *(const float4*)&s_h[t][4*c4i];
      #pragma unroll
      for(int cc=0;cc<4;cc++){
        const int c = 4*c4i + cc;
        const float wxi = in_wT[c*256 + d];
        const float wz  = in_wT[c*256 + 128 + d];
        #pragma unroll
        for(int t=0;t<8;t++){
          const float hv = (cc==0)?h4[t].x:(cc==1)?h4[t].y:(cc==2)?h4[t].z:h4[t].w;
          xi[t] = fmaf(hv, wxi, xi[t]);
          zz[t] = fmaf(hv, wz,  zz[t]);
        }
      }
    }

    // ---- conv + silu (serial in t within thread d) ----
    float xcr[8];
    #pragma unroll
    for(int t=0;t<8;t++){
      float a = cb + cw.x*xm3 + cw.y*xm2 + cw.z*xm1 + cw.w*xi[t];
      xm3 = xm2; xm2 = xm1; xm1 = xi[t];
      float xc = a / (1.f + __expf(-a));
      xcr[t] = xc;
      s_xc[t][d] = xc;
    }
    __syncthreads();   // B

    // ---- x_proj: token g; rows l, l+16, l+32(if l<4) (18KB matrix, L1-hot) ----
    {
      const float* xp1 = xp_w + l*128;
      const float* xp2 = xp_w + (l+16)*128;
      const float* xp3 = xp_w + ((l<4) ? (l+32) : 0)*128;
      float a1=0.f, a2=0.f, a3=0.f;
      #pragma unroll
      for(int q=0;q<32;q++){
        float4 cc4 = *(const float4*)&s_xc[g][4*q];
        float4 w1 = *(const float4*)(xp1 + 4*q);
        float4 w2 = *(const float4*)(xp2 + 4*q);
        float4 w3 = *(const float4*)(xp3 + 4*q);
        a1 = fmaf(cc4.x,w1.x,fmaf(cc4.y,w1.y,fmaf(cc4.z,w1.z,fmaf(cc4.w,w1.w,a1))));
        a2 = fmaf(cc4.x,w2.x,fmaf(cc4.y,w2.y,fmaf(cc4.z,w2.z,fmaf(cc4.w,w2.w,a2))));
        a3 = fmaf(cc4.x,w3.x,fmaf(cc4.y,w3.y,fmaf(cc4.z,w3.z,fmaf(cc4.w,w3.w,a3))));
      }
      s_dbl[g][l]    = a1;
      s_dbl[g][l+16] = a2;
      if(l < 4) s_dbl[g][l+32] = a3;
    }
    __syncthreads();   // C

    // ---- dt + selective scan + readout (thread d, 8 serial steps) ----
    #pragma unroll
    for(int t=0;t<8;t++){
      float4 dr = *(const float4*)&s_dbl[t][0];
      float dtv = dtb;
      dtv = fmaf(dr.x, dtw.x, dtv);
      dtv = fmaf(dr.y, dtw.y, dtv);
      dtv = fmaf(dr.z, dtw.z, dtv);
      dtv = fmaf(dr.w, dtw.w, dtv);
      dtv = fmaxf(dtv, 0.f) + log1pf(__expf(-fabsf(dtv)));
      float dx = dtv * xcr[t];
      float y = 0.f;
      #pragma unroll
      for(int s=0;s<16;s++){
        float dA = __expf(dtv * A_d[s]);
        hs[s] = fmaf(hs[s], dA, dx * s_dbl[t][4+s]);
        y     = fmaf(hs[s], s_dbl[t][20+s], y);
      }
      y = y + Dd * xcr[t];
      y = y * (zz[t] / (1.f + __expf(-zz[t])));   // * silu(z)
      s_y[t][d] = y;
    }
    __syncthreads();   // D

    // ---- out_proj + residual (transposed, coalesced): wave handles 4 tokens ----
    {
      const int tb = (tid >> 6) * 4;
      float acc[4] = {0,0,0,0};
      #pragma unroll
      for(int c4i=0;c4i<32;c4i++){
        float4 y4[4];
        #pragma unroll
        for(int tt=0;tt<4;tt++) y4[tt] = *(const float4*)&s_y[tb+tt][4*c4i];
        #pragma unroll
        for(int cc=0;cc<4;cc++){
          const float w = out_wT[(4*c4i+cc)*64 + r63];
          #pragma unroll
          for(int tt=0;tt<4;tt++){
            const float yv = (cc==0)?y4[tt].x:(cc==1)?y4[tt].y:(cc==2)?y4[tt].z:y4[tt].w;
            acc[tt] = fmaf(yv, w, acc[tt]);
          }
        }
      }
      #pragma unroll
      for(int tt=0;tt<4;tt++){
        const int t = tb + tt;
        const size_t tok = ((size_t)(b*T_LEN + t0 + t)*NODES + n);
        float xn = s_tok[t][r63] + acc[tt];
        s_xn[t][r63] = xn;
        xT[tok*64 + r63] = xn;
      }
    }
    __syncthreads();   // E

    // ---- K/V projection (transposed, coalesced), bf16 store ----
    {
      float kv[8] = {kvb,kvb,kvb,kvb,kvb,kvb,kvb,kvb};
      #pragma unroll
      for(int c4i=0;c4i<16;c4i++){
        float4 x4[8];
        #pragma unroll
        for(int t=0;t<8;t++) x4[t] = *(const float4*)&s_xn[t][4*c4i];
        #pragma unroll
        for(int cc=0;cc<4;cc++){
          const float w = kvT[(4*c4i+cc)*64 + r63];
          #pragma unroll
          for(int t=0;t<8;t++){
            const float xv = (cc==0)?x4[t].x:(cc==1)?x4[t].y:(cc==2)?x4[t].z:x4[t].w;
            kv[t] = fmaf(xv, w, kv[t]);
          }
        }
      }
      #pragma unroll
      for(int t=0;t<8;t++){
        const size_t tok = ((size_t)(b*T_LEN + t0 + t)*NODES + n);
        KV[tok*128 + tid] = __float2bfloat16(kv[t]);
      }
    }
    // next iteration's stage A only touches s_tok/s_h, then barrier A: safe
  }
}

// ================= K2: graph attention + gate + LN2 (in-place on d_out) ======
// 256 threads = 4 waves; wave w handles token blockIdx*4+w. 41600 blocks.
__global__ __launch_bounds__(256)
void attn_fused(float* __restrict__ xT, const bf16* __restrict__ KV,
                const int* __restrict__ nbr,
                const float* __restrict__ q_wT, const float* __restrict__ q_b,
                const float* __restrict__ o_wT, const float* __restrict__ o_b,
                const float* __restrict__ g1_wT, const float* __restrict__ g1_b,
                const float* __restrict__ g2_w, const float* __restrict__ g2_b,
                const float* __restrict__ ln2_g, const float* __restrict__ ln2_b)
{
  const int w   = threadIdx.x >> 6;
  const int j   = threadIdx.x & 63;
  const size_t idx = (size_t)blockIdx.x*4 + w;          // < NTOK exactly
  const int n   = (int)(idx % NODES);
  const size_t base = (idx / NODES) * NODES;

  __shared__ float s_x[4][68];
  __shared__ float s_og[4][68];
  __shared__ float s_gate[4];

  const float xv = xT[idx*64 + j];
  s_x[w][j] = xv;

  // neighbor K/V gather (bf16, precomputed)
  float Kk[TOPK], Vv[TOPK];
  #pragma unroll
  for(int k=0;k<TOPK;k++){
    const int nb = nbr[n*TOPK + k];
    const bf16* kvp = KV + (base + nb)*128;
    Kk[k] = b2f(kvp[j]);
    Vv[k] = b2f(kvp[64 + j]);
  }
  __syncthreads();

  // Q projection (transposed, coalesced)
  float Qj = q_b[j];
  #pragma unroll
  for(int c4i=0;c4i<16;c4i++){
    float4 x4 = *(const float4*)&s_x[w][4*c4i];
    Qj = fmaf(x4.x, q_wT[(4*c4i+0)*64 + j], Qj);
    Qj = fmaf(x4.y, q_wT[(4*c4i+1)*64 + j], Qj);
    Qj = fmaf(x4.z, q_wT[(4*c4i+2)*64 + j], Qj);
    Qj = fmaf(x4.w, q_wT[(4*c4i+3)*64 + j], Qj);
  }

  // head-wise scores + softmax over 8
  float sc[TOPK];
  #pragma unroll
  for(int k=0;k<TOPK;k++) sc[k] = groupSum16(Qj * Kk[k]) * 0.25f;  // hd^-0.5
  float m = sc[0];
  #pragma unroll
  for(int k=1;k<TOPK;k++) m = fmaxf(m, sc[k]);
  float ssum = 0.f;
  #pragma unroll
  for(int k=0;k<TOPK;k++){ sc[k] = __expf(sc[k]-m); ssum += sc[k]; }
  const float inv = 1.f/ssum;
  float og = 0.f;
  #pragma unroll
  for(int k=0;k<TOPK;k++) og = fmaf(sc[k]*inv, Vv[k], og);
  s_og[w][j] = og;
  __syncthreads();

  // O projection (transposed, coalesced)
  float xg = o_b[j];
  #pragma unroll
  for(int c4i=0;c4i<16;c4i++){
    float4 o4 = *(const float4*)&s_og[w][4*c4i];
    xg = fmaf(o4.x, o_wT[(4*c4i+0)*64 + j], xg);
    xg = fmaf(o4.y, o_wT[(4*c4i+1)*64 + j], xg);
    xg = fmaf(o4.z, o_wT[(4*c4i+2)*64 + j], xg);
    xg = fmaf(o4.w, o_wT[(4*c4i+3)*64 + j], xg);
  }

  // scalar gate
  if(j < 16){
    float u = g1_b[j];
    #pragma unroll
    for(int c4i=0;c4i<16;c4i++){
      float4 x4 = *(const float4*)&s_x[w][4*c4i];
      u = fmaf(x4.x, g1_wT[(4*c4i+0)*16 + j], u);
      u = fmaf(x4.y, g1_wT[(4*c4i+1)*16 + j], u);
      u = fmaf(x4.z, g1_wT[(4*c4i+2)*16 + j], u);
      u = fmaf(x4.w, g1_wT[(4*c4i+3)*16 + j], u);
    }
    u = 0.5f * u * (1.f + erff(u * 0.70710678118654752f));   // exact gelu
    float contrib = groupSum16(u * g2_w[j]);
    if(j == 0) s_gate[w] = 1.f / (1.f + __expf(-(contrib + g2_b[0])));
  }
  __syncthreads();

  const float gg = s_gate[w];
  const float o  = xv + gg * (xg - xv);

  // LN2 across the wave's 64 lanes
  float mm  = waveSum64(o) * (1.f/64.f);
  float c   = o - mm;
  float var = waveSum64(c*c) * (1.f/64.f);
  xT[idx*64 + j] = c * rsqrtf(var + EPS) * ln2_g[j] + ln2_b[j];
}

extern "C" void kernel_launch(void* const* d_in, const int* in_sizes, int n_in,
                              void* d_out, int out_size, void* d_ws, size_t ws_size,
                              hipStream_t stream)
{
  const float* x      = (const float*)d_in[0];
  const int*   nbr    = (const int*  )d_in[1];
  const float* ln1_g  = (const float*)d_in[2];
  const float* ln1_b  = (const float*)d_in[3];
  const float* in_w   = (const float*)d_in[4];
  const float* conv_w = (const float*)d_in[5];
  const float* conv_b = (const float*)d_in[6];
  const float* xp_w   = (const float*)d_in[7];
  const float* dt_w   = (const float*)d_in[8];
  const float* dt_b   = (const float*)d_in[9];
  const float* A_log  = (const float*)d_in[10];
  const float* Dss    = (const float*)d_in[11];
  const float* out_w  = (const float*)d_in[12];
  const float* q_w    = (const float*)d_in[13];
  const float* q_b    = (const float*)d_in[14];
  const float* k_w    = (const float*)d_in[15];
  const float* k_b    = (const float*)d_in[16];
  const float* v_w    = (const float*)d_in[17];
  const float* v_b    = (const float*)d_in[18];
  const float* o_w    = (const float*)d_in[19];
  const float* o_b    = (const float*)d_in[20];
  const float* g1_w   = (const float*)d_in[21];
  const float* g1_b   = (const float*)d_in[22];
  const float* g2_w   = (const float*)d_in[23];
  const float* g2_b   = (const float*)d_in[24];
  const float* ln2_g  = (const float*)d_in[25];
  const float* ln2_b  = (const float*)d_in[26];

  bf16* KV = (bf16*)d_ws;                                   // NTOK*128 bf16 = 42.6 MB
  float* T = (float*)((char*)d_ws + NTOK*128*sizeof(bf16)); // +168 KB transposed weights
  float* in_wT  = T;
  float* out_wT = T + 16384;
  float* k_wT   = T + 24576;
  float* v_wT   = T + 28672;
  float* q_wT   = T + 32768;
  float* o_wT   = T + 36864;
  float* g1_wT  = T + 40960;
  float* outp   = (float*)d_out;    // xT between K1/K2, final output after K2

  transpose_prep<<<dim3(164), dim3(256), 0, stream>>>(
      in_w, out_w, k_w, v_w, q_w, o_w, g1_w, T);

  mamba_fused<<<dim3(B_SZ*NODES), dim3(128), 0, stream>>>(
      x, ln1_g, ln1_b, in_wT, conv_w, conv_b, xp_w, dt_w, dt_b, A_log, Dss,
      out_wT, k_wT, k_b, v_wT, v_b, outp, KV);

  attn_fused<<<dim3((unsigned)(NTOK/4)), dim3(256), 0, stream>>>(
      outp, KV, nbr, q_wT, q_b, o_wT, o_b, g1_wT, g1_b, g2_w, g2_b, ln2_g, ln2_b);
}